// Round 1
// baseline (982.490 us; speedup 1.0000x reference)
//
#include <hip/hip_runtime.h>
#include <hip/hip_bf16.h>

#define B_ 8
#define T_ 256
#define U_ 65
#define V_ 1024
#define DIAGS (T_ + U_ - 1)   // 320
#define DSTRIDE (DIAGS * U_)  // 20800 floats per batch per array

// logaddexp(x,y) = max + log1p(exp(-|x-y|)); callers guarantee no -inf inputs
__device__ __forceinline__ float laddexp(float x, float y) {
  float m = fmaxf(x, y);
  return m + log1pf(__expf(-fabsf(x - y)));
}

// Kernel 1: per-row logsumexp over V=1024; emit lp_blank / lp_label in
// diagonal-major layout:
//   blankD[b][(t+u)*U + u]         = lp[b,t,u,0]
//   labelD[b][(t+u+1)*U + (u+1)]   = lp[b,t,u,labels[b,u]]   (u < U-1)
// so kernel 2's per-diagonal reads are contiguous across lanes.
__global__ __launch_bounds__(256) void rnnt_lse_kernel(
    const float* __restrict__ acts, const int* __restrict__ labels,
    float* __restrict__ blankD, float* __restrict__ labelD) {
  const int wave = threadIdx.x >> 6;
  const int lane = threadIdx.x & 63;
  const int row = blockIdx.x * 4 + wave;  // 0 .. B*T*U-1 (exact grid)

  const float* __restrict__ p = acts + (size_t)row * V_;
  const float4* __restrict__ p4 = (const float4*)p;
  // lane i covers float4 indices i, i+64, i+128, i+192 -> coalesced 1KB/instr
  float4 v0 = p4[lane];
  float4 v1 = p4[64 + lane];
  float4 v2 = p4[128 + lane];
  float4 v3 = p4[192 + lane];

  float m = fmaxf(fmaxf(fmaxf(v0.x, v0.y), fmaxf(v0.z, v0.w)),
                  fmaxf(fmaxf(v1.x, v1.y), fmaxf(v1.z, v1.w)));
  m = fmaxf(m, fmaxf(fmaxf(fmaxf(v2.x, v2.y), fmaxf(v2.z, v2.w)),
                     fmaxf(fmaxf(v3.x, v3.y), fmaxf(v3.z, v3.w))));
  #pragma unroll
  for (int off = 32; off; off >>= 1) m = fmaxf(m, __shfl_xor(m, off, 64));

  float s = (__expf(v0.x - m) + __expf(v0.y - m)) +
            (__expf(v0.z - m) + __expf(v0.w - m));
  s += (__expf(v1.x - m) + __expf(v1.y - m)) +
       (__expf(v1.z - m) + __expf(v1.w - m));
  s += (__expf(v2.x - m) + __expf(v2.y - m)) +
       (__expf(v2.z - m) + __expf(v2.w - m));
  s += (__expf(v3.x - m) + __expf(v3.y - m)) +
       (__expf(v3.z - m) + __expf(v3.w - m));
  #pragma unroll
  for (int off = 32; off; off >>= 1) s += __shfl_xor(s, off, 64);

  float lse = m + __logf(s);

  if (lane == 0) {
    const int b = row / (T_ * U_);
    const int rem = row - b * (T_ * U_);
    const int t = rem / U_;
    const int u = rem - t * U_;
    // p[0] is v0.x on lane 0
    blankD[b * DSTRIDE + (t + u) * U_ + u] = v0.x - lse;
    if (u < U_ - 1) {
      const int lab = labels[b * (U_ - 1) + u];
      labelD[b * DSTRIDE + (t + u + 1) * U_ + (u + 1)] = p[lab] - lse;  // L1 hit
    }
  }
}

// Kernel 2: one wave per batch. Anti-diagonal wavefront d = t+u.
// Lane u holds alpha[., u] in a register; lane 63 additionally holds u=64.
// alpha[t,u] = logaddexp(alpha[t-1,u] + lp_blank[b,t-1,u],
//                        alpha[t,u-1] + lp_label[b,t,u-1])
__global__ __launch_bounds__(64) void rnnt_alpha_kernel(
    const float* __restrict__ blankD, const float* __restrict__ labelD,
    const int* __restrict__ act_lens, const int* __restrict__ label_lens,
    float* __restrict__ out) {
  const int b = blockIdx.x;
  const int lane = threadIdx.x;  // 0..63
  const float* __restrict__ BD = blankD + b * DSTRIDE;
  const float* __restrict__ LD = labelD + b * DSTRIDE;

  const int t_end = act_lens[b] - 1;   // >= 127
  const int u_end = label_lens[b];     // 32..64
  const int d_end = t_end + u_end;     // <= 319

  float a = 0.f;    // alpha on previous diagonal at u = lane
  float a64 = 0.f;  // lane 63: alpha at u = 64
  // prefetched lp values for the *current* diagonal d:
  //   bd  = BD[(d-1)*U + lane], ld  = LD[d*U + lane]  (garbage at d=0; unused)
  float bd = 0.f, ld = 0.f, bd64 = 0.f, ld64 = 0.f;

  for (int d = 0; d <= d_end; ++d) {
    const float am1 = __shfl_up(a, 1, 64);  // alpha[d-1][lane-1]
    const float prev_a = a;
    const float prev_a64 = a64;

    const int t = d - lane;
    if (t >= 0 && t < T_) {
      float na;
      if (t == 0) {
        na = (lane == 0) ? 0.f : (am1 + ld);       // label-only edge
      } else if (lane == 0) {
        na = prev_a + bd;                           // blank-only edge
      } else {
        na = laddexp(prev_a + bd, am1 + ld);
      }
      a = na;
    }
    if (lane == 63) {  // u = 64: prev[63] is this lane's prev_a
      const int t64 = d - 64;
      if (t64 >= 0 && t64 < T_) {
        a64 = (t64 == 0) ? (prev_a + ld64)
                         : laddexp(prev_a64 + bd64, prev_a + ld64);
      }
    }

    if (d == d_end) {
      float res;
      bool mine = false;
      if (u_end == 64) {
        if (lane == 63) { res = a64; mine = true; }
      } else if (lane == u_end) {
        res = a; mine = true;
      }
      if (mine) {
        const float ll = res + BD[d * U_ + u_end];  // + lp_blank at (t_end,u_end)
        atomicAdd(out, -ll * (1.0f / B_));
      }
    }

    // prefetch lp values for diagonal d+1 (clamped; OOB lanes' values unused)
    const int dn = (d + 1 < DIAGS) ? (d + 1) : (DIAGS - 1);
    bd = BD[d * U_ + lane];
    ld = LD[dn * U_ + lane];
    bd64 = BD[d * U_ + 64];   // uniform broadcast loads
    ld64 = LD[dn * U_ + 64];
  }
}

extern "C" void kernel_launch(void* const* d_in, const int* in_sizes, int n_in,
                              void* d_out, int out_size, void* d_ws, size_t ws_size,
                              hipStream_t stream) {
  const float* acts = (const float*)d_in[0];
  const int* labels = (const int*)d_in[1];
  const int* act_lens = (const int*)d_in[2];
  const int* label_lens = (const int*)d_in[3];
  float* out = (float*)d_out;

  float* blankD = (float*)d_ws;                 // B*DSTRIDE floats
  float* labelD = blankD + (size_t)B_ * DSTRIDE;

  // d_out is re-poisoned to 0xAA before every replay; zero it for atomicAdd.
  hipMemsetAsync(out, 0, sizeof(float), stream);

  const int rows = B_ * T_ * U_;  // 133120, divisible by 4
  rnnt_lse_kernel<<<rows / 4, 256, 0, stream>>>(acts, labels, blankD, labelD);
  rnnt_alpha_kernel<<<B_, 64, 0, stream>>>(blankD, labelD, act_lens, label_lens, out);
}

// Round 2
// 748.667 us; speedup vs baseline: 1.3123x; 1.3123x over previous
//
#include <hip/hip_runtime.h>
#include <hip/hip_bf16.h>

#define B_ 8
#define T_ 256
#define U_ 65
#define V_ 1024
#define DIAGS (T_ + U_ - 1)   // 320
#define DSTRIDE (DIAGS * U_)  // 20800 floats per batch per array
#define PF 8                  // prefetch depth for alpha kernel (DIAGS % PF == 0)

// fast logaddexp: max + log(1+exp(-|x-y|)); inputs finite by construction.
// __logf/__expf (v_log_f32/v_exp_f32) — rel err ~1e-6, absmax budget is 29.
__device__ __forceinline__ float laddexp(float x, float y) {
  float m = fmaxf(x, y);
  return m + __logf(1.0f + __expf(-fabsf(x - y)));
}

// Kernel 1: per-row logsumexp over V=1024; emit lp_blank / lp_label in
// diagonal-major layout:
//   blankD[b][(t+u)*U + u]         = lp[b,t,u,0]
//   labelD[b][(t+u+1)*U + (u+1)]   = lp[b,t,u,labels[b,u]]   (u < U-1)
// so kernel 2's per-diagonal reads are contiguous across lanes.
// Memory-bound: 545 MB read once; one wave per row, 4x dwordx4 per lane.
__global__ __launch_bounds__(256) void rnnt_lse_kernel(
    const float* __restrict__ acts, const int* __restrict__ labels,
    float* __restrict__ blankD, float* __restrict__ labelD) {
  const int wave = threadIdx.x >> 6;
  const int lane = threadIdx.x & 63;
  const int row = blockIdx.x * 4 + wave;  // 0 .. B*T*U-1 (exact grid)

  const float* __restrict__ p = acts + (size_t)row * V_;
  const float4* __restrict__ p4 = (const float4*)p;
  // lane i covers float4 indices i, i+64, i+128, i+192 -> coalesced 1KB/instr
  float4 v0 = p4[lane];
  float4 v1 = p4[64 + lane];
  float4 v2 = p4[128 + lane];
  float4 v3 = p4[192 + lane];

  float m = fmaxf(fmaxf(fmaxf(v0.x, v0.y), fmaxf(v0.z, v0.w)),
                  fmaxf(fmaxf(v1.x, v1.y), fmaxf(v1.z, v1.w)));
  m = fmaxf(m, fmaxf(fmaxf(fmaxf(v2.x, v2.y), fmaxf(v2.z, v2.w)),
                     fmaxf(fmaxf(v3.x, v3.y), fmaxf(v3.z, v3.w))));
  #pragma unroll
  for (int off = 32; off; off >>= 1) m = fmaxf(m, __shfl_xor(m, off, 64));

  float s = (__expf(v0.x - m) + __expf(v0.y - m)) +
            (__expf(v0.z - m) + __expf(v0.w - m));
  s += (__expf(v1.x - m) + __expf(v1.y - m)) +
       (__expf(v1.z - m) + __expf(v1.w - m));
  s += (__expf(v2.x - m) + __expf(v2.y - m)) +
       (__expf(v2.z - m) + __expf(v2.w - m));
  s += (__expf(v3.x - m) + __expf(v3.y - m)) +
       (__expf(v3.z - m) + __expf(v3.w - m));
  #pragma unroll
  for (int off = 32; off; off >>= 1) s += __shfl_xor(s, off, 64);

  float lse = m + __logf(s);

  if (lane == 0) {
    const int b = row / (T_ * U_);
    const int rem = row - b * (T_ * U_);
    const int t = rem / U_;
    const int u = rem - t * U_;
    // p[0] is v0.x on lane 0
    blankD[b * DSTRIDE + (t + u) * U_ + u] = v0.x - lse;
    if (u < U_ - 1) {
      const int lab = labels[b * (U_ - 1) + u];
      labelD[b * DSTRIDE + (t + u + 1) * U_ + (u + 1)] = p[lab] - lse;  // L1 hit
    }
  }
}

// Kernel 2: ONE block, 8 waves; wave b owns batch b. Anti-diagonal wavefront
// d = t+u, lane u holds alpha[., u] in a register (lane 63 also carries u=64).
//   alpha[t,u] = logaddexp(alpha[t-1,u] + lp_blank[t-1,u],
//                          alpha[t,u-1] + lp_label[t,u-1])
// Rolling register prefetch of depth PF=8 hides L2/L3 load latency; the
// per-diagonal critical path is shfl_up + add + fast-logaddexp (~80 cy).
// Final: per-wave result -> LDS -> thread 0 sums and writes out (no atomic,
// no memset dispatch).
__global__ __launch_bounds__(512) void rnnt_alpha_kernel(
    const float* __restrict__ blankD, const float* __restrict__ labelD,
    const int* __restrict__ act_lens, const int* __restrict__ label_lens,
    float* __restrict__ out) {
  const int wv = threadIdx.x >> 6;   // batch 0..7
  const int lane = threadIdx.x & 63;
  const float* __restrict__ BD = blankD + wv * DSTRIDE;
  const float* __restrict__ LD = labelD + wv * DSTRIDE;

  const int t_end = act_lens[wv] - 1;   // >= 127
  const int u_end = label_lens[wv];     // 32..64
  const int d_end = t_end + u_end;      // <= 319
  const bool use64 = (u_end == 64);

  float a = 0.f;    // alpha at u = lane on the current wavefront
  float a64 = 0.f;  // lane 63: alpha at u = 64
  float cap = 0.f;  // captured alpha[t_end, u_end] (valid on owner lane)

  // Rolling prefetch buffers: slot j holds the lp values needed at d = base+j:
  //   bdb[j] = BD[(d-1)*U + lane], ldb[j] = LD[d*U + lane]  (+ u=64 broadcasts)
  float bdb[PF], ldb[PF], bdb64[PF], ldb64[PF];
  #pragma unroll
  for (int j = 0; j < PF; ++j) {
    const int rb = (j >= 1) ? (j - 1) : 0;  // d=0 blank row unused; any valid row
    bdb[j] = BD[rb * U_ + lane];
    ldb[j] = LD[j * U_ + lane];
    bdb64[j] = BD[rb * U_ + 64];
    ldb64[j] = LD[j * U_ + 64];
  }

  for (int d = 0; d <= d_end; d += PF) {
    #pragma unroll
    for (int j = 0; j < PF; ++j) {
      const int dd = d + j;
      const float am1 = __shfl_up(a, 1, 64);  // alpha[prev diag][lane-1]
      const float pa = a;
      const float pa64 = a64;
      const float bd = bdb[j];
      const float ld = ldb[j];

      const int t = dd - lane;
      if (t >= 0 && t < T_) {
        float na;
        if (t == 0) {
          na = (lane == 0) ? 0.f : (am1 + ld);   // label-only edge
        } else if (lane == 0) {
          na = pa + bd;                           // blank-only edge
        } else {
          na = laddexp(pa + bd, am1 + ld);
        }
        a = na;
      }
      if (lane == 63) {  // u = 64: "u-1" neighbor is this lane's own pa
        const int t64 = dd - 64;
        if (t64 >= 0 && t64 < T_) {
          a64 = (t64 == 0) ? (pa + ldb64[j])
                           : laddexp(pa64 + bdb64[j], pa + ldb64[j]);
        }
      }
      if (dd == d_end) cap = use64 ? a64 : a;   // wave-uniform condition

      // refill slot j for iteration dd+PF (clamped; clamped rows' values
      // are only consumed by t-masked lanes or past-d_end stages)
      int rb2 = dd + PF - 1; if (rb2 >= DIAGS) rb2 = DIAGS - 1;
      int rl2 = dd + PF;     if (rl2 >= DIAGS) rl2 = DIAGS - 1;
      bdb[j] = BD[rb2 * U_ + lane];
      ldb[j] = LD[rl2 * U_ + lane];
      bdb64[j] = BD[rb2 * U_ + 64];
      ldb64[j] = LD[rl2 * U_ + 64];
    }
  }

  const int src = use64 ? 63 : u_end;
  const float alpha_end = __shfl(cap, src, 64);

  __shared__ float partial[B_];
  if (lane == 0) {
    // ll = alpha[t_end,u_end] + lp_blank[t_end,u_end]
    partial[wv] = -(alpha_end + BD[d_end * U_ + u_end]) * (1.0f / B_);
  }
  __syncthreads();
  if (threadIdx.x == 0) {
    float s = 0.f;
    #pragma unroll
    for (int i = 0; i < B_; ++i) s += partial[i];
    out[0] = s;   // overwrites poison; no memset needed
  }
}

extern "C" void kernel_launch(void* const* d_in, const int* in_sizes, int n_in,
                              void* d_out, int out_size, void* d_ws, size_t ws_size,
                              hipStream_t stream) {
  const float* acts = (const float*)d_in[0];
  const int* labels = (const int*)d_in[1];
  const int* act_lens = (const int*)d_in[2];
  const int* label_lens = (const int*)d_in[3];
  float* out = (float*)d_out;

  float* blankD = (float*)d_ws;                 // B*DSTRIDE floats
  float* labelD = blankD + (size_t)B_ * DSTRIDE;

  const int rows = B_ * T_ * U_;  // 133120, divisible by 4
  rnnt_lse_kernel<<<rows / 4, 256, 0, stream>>>(acts, labels, blankD, labelD);
  rnnt_alpha_kernel<<<1, 512, 0, stream>>>(blankD, labelD, act_lens, label_lens, out);
}